// Round 16
// baseline (86.414 us; speedup 1.0000x reference)
//
#include <hip/hip_runtime.h>
#include <stdint.h>

typedef __attribute__((ext_vector_type(8))) short short8;        // 8 x bf16 (4 VGPRs)
typedef __attribute__((ext_vector_type(4))) float f32x4;
typedef __attribute__((ext_vector_type(16))) float f32x16;
typedef __attribute__((ext_vector_type(4))) unsigned int u32x4;

#define MFMA16(a, b, c) __builtin_amdgcn_mfma_f32_16x16x32_bf16((a), (b), (c), 0, 0, 0)
#define MFMA32(a, b, c) __builtin_amdgcn_mfma_f32_32x32x16_bf16((a), (b), (c), 0, 0, 0)

#define GLOAD_LDS16(gsrc, ldst)                                                        \
    __builtin_amdgcn_global_load_lds(                                                  \
        (const __attribute__((address_space(1))) unsigned int*)(gsrc),                 \
        (__attribute__((address_space(3))) unsigned int*)(ldst), 16, 0, 0)

#define LOG2E 1.4426950408889634f

static __device__ __forceinline__ unsigned short f2bf(float f) {
    union { float f; unsigned int u; } v; v.f = f;
    unsigned int u = v.u;
    unsigned int r = 0x7fffu + ((u >> 16) & 1u);
    return (unsigned short)((u + r) >> 16);
}

static __device__ __forceinline__ float bf2f(unsigned short s) {
    union { unsigned int u; float f; } v; v.u = ((unsigned int)s) << 16;
    return v.f;
}

static __device__ __forceinline__ unsigned int cvt_pk_bf16(float lo, float hi) {
    unsigned int r;
    asm("v_cvt_pk_bf16_f32 %0, %1, %2" : "=v"(r) : "v"(lo), "v"(hi));
    return r;
}

// raw v_exp_f32: single instruction, exact for our |S| << 30 range (no OCML wrapper).
static __device__ __forceinline__ float fexp2(float x) {
#if __has_builtin(__builtin_amdgcn_exp2f)
    return __builtin_amdgcn_exp2f(x);
#else
    return exp2f(x);
#endif
}

// ---------------- Kernel 0: convert Wq|Wk|Wv f32 -> bf16 once ----------------
// Wb layout: [0,8192) Wq, [8192,16384) Wk, [16384,81920) Wv.
__global__ __launch_bounds__(256) void k_prepw(const float* __restrict__ Wq,
                                               const float* __restrict__ Wk,
                                               const float* __restrict__ Wv,
                                               unsigned short* __restrict__ Wb) {
    const int i = (blockIdx.x * 256 + threadIdx.x) * 4;
    const float* src; int off;
    if (i < 8192)       { src = Wq; off = i; }
    else if (i < 16384) { src = Wk; off = i - 8192; }
    else                { src = Wv; off = i - 16384; }
    const float4 v = *(const float4*)(src + off);
    ushort4 o;
    o.x = f2bf(v.x); o.y = f2bf(v.y); o.z = f2bf(v.z); o.w = f2bf(v.w);
    *(ushort4*)(Wb + i) = o;
}

// ---------------- Kernel 1: fused QKV projection, c-split for TLP ----------------
// grid (64, B, 2). Half 0: q,k + V rows [0,128); half 1: V rows [128,256).
// v epilogue writes vp with the 32x32-MFMA 64-i permutation k_attn expects:
// i_local = 16*wv + l15 -> unit u = 2*wv + h (h=(l15>>2)&1), elem e = (l15&3)+4*(l15>>3);
// jp = u*8 + e. (k_attn A-frag for PV MFMA j, lane-half h reads unit u = 2j + h.)
__global__ __launch_bounds__(256) void k_qkv(const float* __restrict__ x,
                                             const unsigned short* __restrict__ Wb,
                                             const float* __restrict__ bq,
                                             const float* __restrict__ bk,
                                             const float* __restrict__ bv,
                                             unsigned short* __restrict__ qT,
                                             unsigned short* __restrict__ kT,
                                             unsigned short* __restrict__ vp) {
    const int b = blockIdx.y;
    const int nt = blockIdx.x;                    // 64-n tile
    const int h = blockIdx.z;                     // c-half of V
    const int lane = threadIdx.x & 63;
    const int wv = threadIdx.x >> 6;              // 0..3: wave's 16-n sub-tile
    const int l15 = lane & 15, g = lane >> 4;
    const int n0 = nt * 64;
    const int nw = n0 + wv * 16;

    const float* xb = x + (size_t)b * 1048576;    // [256 c][4096 n]
    const float* xs = xb + (size_t)(g * 8) * 4096 + nw + l15;

    const unsigned short* Wqb = Wb;
    const unsigned short* Wkb = Wb + 8192;
    const unsigned short* Wvb = Wb + 16384 + h * 32768;   // 128 rows x 256

    f32x4 aqk[4] = {};                            // q0,q1,k0,k1 (half 0 only)
    f32x4 av[8] = {};

#pragma unroll 2
    for (int k0 = 0; k0 < 256; k0 += 32) {
        const float* xp = xs + (size_t)k0 * 4096;
        float xv[8];
#pragma unroll
        for (int j = 0; j < 8; ++j) xv[j] = xp[(size_t)j * 4096];
        const u32x4 ux = {cvt_pk_bf16(xv[0], xv[1]), cvt_pk_bf16(xv[2], xv[3]),
                          cvt_pk_bf16(xv[4], xv[5]), cvt_pk_bf16(xv[6], xv[7])};
        const short8 xa = __builtin_bit_cast(short8, ux);

        if (h == 0) {
#pragma unroll
            for (int ot = 0; ot < 4; ++ot) {
                const unsigned short* wr = (ot < 2) ? (Wqb + (size_t)(ot * 16 + l15) * 256)
                                                    : (Wkb + (size_t)((ot - 2) * 16 + l15) * 256);
                const short8 wb8 = *(const short8*)(wr + k0 + g * 8);
                aqk[ot] = MFMA16(xa, wb8, aqk[ot]);
            }
        }
#pragma unroll
        for (int ct = 0; ct < 8; ++ct) {
            const short8 wv8 = *(const short8*)(Wvb + (size_t)(ct * 16 + l15) * 256 + k0 + g * 8);
            av[ct] = MFMA16(wv8, xa, av[ct]);
        }
    }

    if (h == 0) {
#pragma unroll
        for (int ot = 0; ot < 4; ++ot) {
            const int o = (ot & 1) * 16 + l15;
            const float bias = (ot < 2) ? bq[o] : bk[o];
            const float sc = (ot < 2) ? LOG2E : 1.0f;
            unsigned short* dst = (ot < 2) ? qT : kT;
#pragma unroll
            for (int r = 0; r < 4; ++r) {
                const int n = nw + g * 4 + r;
                dst[((size_t)b * 4096 + n) * 32 + o] = f2bf((aqk[ot][r] + bias) * sc);
            }
        }
    }
    // ---- v epilogue: 32x32 k-order permutation ----
    const int jp = (2 * wv + ((l15 >> 2) & 1)) * 8 + (l15 & 3) + ((l15 >> 3) << 2);
#pragma unroll
    for (int ct = 0; ct < 8; ++ct)
#pragma unroll
        for (int r = 0; r < 4; ++r) {
            const int c = h * 128 + ct * 16 + g * 4 + r;
            vp[((size_t)b * 256 + c) * 4096 + n0 + jp] = f2bf(av[ct][r] + bv[c]);
        }
}

// ---------------- Kernel 2: flash attention; 32x32x16 MFMA ---------------------------
// No-max softmax: P = exp2(S). Wave covers 32 m, all 256 c; 64-i tiles, dbuf LDS.
// QK: A=q (rows i=l31), B=k (cols m=l31), K=d split in 2 halves (d = 8h+e / 16+8h+e).
// D layout (m74/m101): col=lane&31=m, row=(r&3)+8*(r>>2)+4h -> lane holds one m, 32 i.
// PV B-frags = sequential P reg slices (pb_j = pack(P[8j..8j+7])), lane-local.
// PV A (V): unit u = 2j + h per c-row, pre-permuted by k_qkv; LDS slot = u ^ (c&7).
__global__ __launch_bounds__(256, 2) void k_attn(const unsigned short* __restrict__ qT,
                                                 const unsigned short* __restrict__ kT,
                                                 const unsigned short* __restrict__ vp,
                                                 unsigned short* __restrict__ Opart,
                                                 float* __restrict__ mll,
                                                 int ilen) {
    // [2 buf][256 c][64 i'] bf16; 16B chunk (c, slot) holds unit u = slot ^ (c&7). 64 KiB.
    __shared__ __align__(16) unsigned short vlds[2 * 16384];

    const int b = blockIdx.y;
    const int mt = blockIdx.x;
    const int sp = blockIdx.z;
    const int tid = threadIdx.x;
    const int lane = tid & 63;
    const int wv = tid >> 6;
    const int l31 = lane & 31, h = lane >> 5;
    const int m_base = mt * 128 + wv * 32;
    const int i_start = sp * ilen;
    const int T = ilen >> 6;

    const unsigned short* qTb = qT + (size_t)b * 131072;
    const unsigned short* vpb = vp + (size_t)b * 1048576;

    // hoisted QK B-frags (k), d-halves
    const unsigned short* krow = kT + ((size_t)b * 4096 + m_base + l31) * 32 + h * 8;
    const short8 qkB0 = *(const short8*)(krow);         // d = 8h + e
    const short8 qkB1 = *(const short8*)(krow + 16);    // d = 16 + 8h + e

    // staging (byte-identical to R12): lane -> (c = 64wv + 8s + (lane>>3), slot = lane&7);
    // source pre-swizzled: jd = (lane&7) ^ ((lane>>3)&7).
    const int jd = (lane & 7) ^ ((lane >> 3) & 7);
    const unsigned short* vsrc = vpb + (size_t)(64 * wv + (lane >> 3)) * 4096 + i_start + jd * 8;
    const int ldst0 = wv * 4096;

#define STAGE(bufsel, ioff)                                                             \
    do {                                                                                \
        _Pragma("unroll")                                                               \
        for (int s_ = 0; s_ < 8; ++s_)                                                  \
            GLOAD_LDS16(vsrc + (size_t)s_ * 32768 + (ioff),                             \
                        vlds + (bufsel) * 16384 + ldst0 + s_ * 512);                    \
    } while (0)

    // PV A-frag offsets: row c = cb*32 + l31; unit u = 2j + h; slot = u ^ (l31&7).
    const int rd0 = l31 * 64 + (((2 * 0 + h) ^ (l31 & 7)) << 3);
    const int rd1 = l31 * 64 + (((2 * 1 + h) ^ (l31 & 7)) << 3);
    const int rd2 = l31 * 64 + (((2 * 2 + h) ^ (l31 & 7)) << 3);
    const int rd3 = l31 * 64 + (((2 * 3 + h) ^ (l31 & 7)) << 3);

    const unsigned short* qp = qTb + (size_t)(i_start + l31) * 32 + h * 8;

    f32x16 oacc[8] = {};
    float l_acc = 0.0f;
    f32x16 zf16;
#pragma unroll
    for (int r = 0; r < 16; ++r) zf16[r] = 0.0f;

    STAGE(0, 0);
    __syncthreads();

    for (int t = 0; t < T; ++t) {
        const int cur = t & 1;
        if (t + 1 < T) STAGE(cur ^ 1, (t + 1) * 64);

        // ---- QK^T: 2 i-blocks x 2 d-halves ----
        const short8 qa00 = *(const short8*)(qp);           // iblock 0, d 0..15
        const short8 qa01 = *(const short8*)(qp + 16);      // iblock 0, d 16..31
        const short8 qa10 = *(const short8*)(qp + 1024);    // iblock 1, d 0..15
        const short8 qa11 = *(const short8*)(qp + 1040);    // iblock 1, d 16..31
        qp += 2048;
        f32x16 P0 = MFMA32(qa00, qkB0, zf16);
        P0 = MFMA32(qa01, qkB1, P0);
        f32x16 P1 = MFMA32(qa10, qkB0, zf16);
        P1 = MFMA32(qa11, qkB1, P1);

        // ---- P = exp2(S); per-lane l sum (lane owns one m) ----
        float s = 0.f;
#pragma unroll
        for (int r = 0; r < 16; ++r) {
            P0[r] = fexp2(P0[r]); s += P0[r];
            P1[r] = fexp2(P1[r]); s += P1[r];
        }
        l_acc += s;

        // ---- pack 4 PV B-frags: pb_j = P regs 8j..8j+7 (lane-local) ----
        const u32x4 u0 = {cvt_pk_bf16(P0[0], P0[1]), cvt_pk_bf16(P0[2], P0[3]),
                          cvt_pk_bf16(P0[4], P0[5]), cvt_pk_bf16(P0[6], P0[7])};
        const u32x4 u1 = {cvt_pk_bf16(P0[8], P0[9]), cvt_pk_bf16(P0[10], P0[11]),
                          cvt_pk_bf16(P0[12], P0[13]), cvt_pk_bf16(P0[14], P0[15])};
        const u32x4 u2 = {cvt_pk_bf16(P1[0], P1[1]), cvt_pk_bf16(P1[2], P1[3]),
                          cvt_pk_bf16(P1[4], P1[5]), cvt_pk_bf16(P1[6], P1[7])};
        const u32x4 u3 = {cvt_pk_bf16(P1[8], P1[9]), cvt_pk_bf16(P1[10], P1[11]),
                          cvt_pk_bf16(P1[12], P1[13]), cvt_pk_bf16(P1[14], P1[15])};
        const short8 pb0 = __builtin_bit_cast(short8, u0);
        const short8 pb1 = __builtin_bit_cast(short8, u1);
        const short8 pb2 = __builtin_bit_cast(short8, u2);
        const short8 pb3 = __builtin_bit_cast(short8, u3);

        // ---- PV: 8 c-blocks x 4 K-steps; one b128 V read per MFMA ----
        const unsigned short* vb = vlds + cur * 16384;
        __builtin_amdgcn_s_setprio(1);
#pragma unroll
        for (int cb = 0; cb < 8; ++cb) {
            const unsigned short* vr = vb + cb * 2048;
            const short8 va0 = *(const short8*)(vr + rd0);
            const short8 va1 = *(const short8*)(vr + rd1);
            const short8 va2 = *(const short8*)(vr + rd2);
            const short8 va3 = *(const short8*)(vr + rd3);
            oacc[cb] = MFMA32(va0, pb0, oacc[cb]);
            oacc[cb] = MFMA32(va1, pb1, oacc[cb]);
            oacc[cb] = MFMA32(va2, pb2, oacc[cb]);
            oacc[cb] = MFMA32(va3, pb3, oacc[cb]);
        }
        __builtin_amdgcn_s_setprio(0);

        if (t + 1 < T) __syncthreads();
    }
#undef STAGE

    // ---- epilogue: raw partial O (bf16) and per-m l sums ----
    unsigned short* Ob = Opart + (size_t)(sp * 4 + b) * 1048576;
#pragma unroll
    for (int cb = 0; cb < 8; ++cb)
#pragma unroll
        for (int r = 0; r < 16; ++r) {
            const int c = cb * 32 + (r & 3) + 8 * (r >> 2) + 4 * h;
            Ob[(size_t)c * 4096 + m_base + l31] = f2bf(oacc[cb][r]);
        }
    float l0 = l_acc + __shfl_xor(l_acc, 32);
    if (lane < 32) {
        mll[(size_t)(sp * 4 + b) * 4096 + m_base + l31] = l0;
    }
}

// ---------------- Kernel 3: combine partials (pure sum) + gamma*O/L + x ----------------
// grid: 4*256*4096 / (256 threads * 8 elements) = 2048 blocks
__global__ __launch_bounds__(256) void k_combine(const unsigned short* __restrict__ Opart,
                                                 const float* __restrict__ mll,
                                                 const float* __restrict__ x,
                                                 const float* __restrict__ gamma,
                                                 float* __restrict__ out, int S) {
    const size_t e0 = ((size_t)blockIdx.x * 256 + threadIdx.x) * 8;   // < 4,194,304
    const int m0 = (int)(e0 & 4095);
    const int b = (int)(e0 >> 20);

    float L[8] = {}, O[8] = {};
    for (int s = 0; s < S; ++s) {
        const size_t base = (size_t)(s * 4 + b) * 4096 + m0;
        const float4 la = *(const float4*)(mll + base);
        const float4 lc = *(const float4*)(mll + base + 4);
        const short8 op = *(const short8*)(Opart + (size_t)s * 4194304 + e0);
        L[0] += la.x; O[0] += bf2f((unsigned short)op[0]);
        L[1] += la.y; O[1] += bf2f((unsigned short)op[1]);
        L[2] += la.z; O[2] += bf2f((unsigned short)op[2]);
        L[3] += la.w; O[3] += bf2f((unsigned short)op[3]);
        L[4] += lc.x; O[4] += bf2f((unsigned short)op[4]);
        L[5] += lc.y; O[5] += bf2f((unsigned short)op[5]);
        L[6] += lc.z; O[6] += bf2f((unsigned short)op[6]);
        L[7] += lc.w; O[7] += bf2f((unsigned short)op[7]);
    }

    const float g0 = gamma[0];
    const float4 x0 = *(const float4*)(x + e0);
    const float4 x1 = *(const float4*)(x + e0 + 4);
    float4 o0, o1;
    o0.x = g0 * O[0] / L[0] + x0.x; o0.y = g0 * O[1] / L[1] + x0.y;
    o0.z = g0 * O[2] / L[2] + x0.z; o0.w = g0 * O[3] / L[3] + x0.w;
    o1.x = g0 * O[4] / L[4] + x1.x; o1.y = g0 * O[5] / L[5] + x1.y;
    o1.z = g0 * O[6] / L[6] + x1.z; o1.w = g0 * O[7] / L[7] + x1.w;
    *(float4*)(out + e0) = o0;
    *(float4*)(out + e0 + 4) = o1;
}

extern "C" void kernel_launch(void* const* d_in, const int* in_sizes, int n_in,
                              void* d_out, int out_size, void* d_ws, size_t ws_size,
                              hipStream_t stream) {
    (void)in_sizes; (void)n_in; (void)out_size;
    const float* x     = (const float*)d_in[0];
    const float* Wq    = (const float*)d_in[1];
    const float* bq    = (const float*)d_in[2];
    const float* Wk    = (const float*)d_in[3];
    const float* bk    = (const float*)d_in[4];
    const float* Wv    = (const float*)d_in[5];
    const float* bv    = (const float*)d_in[6];
    const float* gamma = (const float*)d_in[7];
    float* out = (float*)d_out;

    unsigned short* qT = (unsigned short*)d_ws;                       // 4*4096*32 bf16
    unsigned short* kT = qT + (size_t)4 * 4096 * 32;                  // 4*4096*32
    unsigned short* vp = kT + (size_t)4 * 4096 * 32;                  // 4*256*4096
    unsigned short* Wb = vp + (size_t)4 * 256 * 4096;                 // 81920 bf16
    unsigned short* Opart = Wb + 81920;                               // S * 4*256*4096 bf16

    const size_t base_el = 2 * (size_t)4 * 4096 * 32 + (size_t)4 * 256 * 4096 + 81920;
    auto need = [&](int s) {
        return (base_el + (size_t)s * 4194304) * 2 + (size_t)s * 16384 * 4;
    };
    const int S = (need(4) <= ws_size) ? 4 : (need(2) <= ws_size) ? 2 : 1;
    float* mll = (float*)(Opart + (size_t)S * 4194304);

    k_prepw<<<dim3(80), 256, 0, stream>>>(Wq, Wk, Wv, Wb);
    k_qkv<<<dim3(64, 4, 2), 256, 0, stream>>>(x, Wb, bq, bk, bv, qT, kT, vp);
    k_attn<<<dim3(32, 4, S), 256, 0, stream>>>(qT, kT, vp, Opart, mll, 4096 / S);
    k_combine<<<dim3(2048), 256, 0, stream>>>(Opart, mll, x, gamma, out, S);
}